// Round 12
// baseline (108.542 us; speedup 1.0000x reference)
//
#include <hip/hip_runtime.h>

#define IN_F  4096
#define OUT_F 32000
#define KC    64           // k per tile
#define NT    (IN_F / KC)  // 64 tiles
#define BM    16           // out-channels per block (one wave)

typedef __attribute__((ext_vector_type(8))) short bf16x8;
typedef __attribute__((ext_vector_type(4))) float f32x4;
typedef unsigned int u32;

__device__ __forceinline__ short bf(float f) {
    __bf16 h = (__bf16)f;
    short s;
    __builtin_memcpy(&s, &h, 2);
    return s;
}

// HBM -> LDS direct (16B/lane). LDS dest = wave-uniform base + lane*16;
// per-lane global source carries the swizzle. (Proven R7/R11.)
__device__ __forceinline__ void gload16(const void* g, void* l) {
    __builtin_amdgcn_global_load_lds(
        (const __attribute__((address_space(1))) u32*)g,
        (__attribute__((address_space(3))) u32*)l, 16, 0, 0);
}

// W-row swizzle: for 256-B rows (KC=64 int32) the granule map
// g = (r&7)<<1 | (r>>3) is bijective over [0,16); fragment ds_read_b128
// lands the uniform 8-accesses-per-bank minimum (re-derived for KC=64).
__device__ __forceinline__ int swzW(int r) {
    return ((r & 7) << 5) | (((r >> 3) & 1) << 4);
}

// 1 wave per block, 16 out-ch x 16 batch, KC=64, grid 2000 -> ~7.8
// independent block pipelines per CU (R11 confirmed this axis: 2->4
// pipelines gave +5.4%). LDS 12 KB. W via global_load_lds (raw int32,
// double-buffered, source-pre-swizzled); X reg-staged -> bf16 LDS.
// One barrier per tile with explicit full waitcnt (guards against
// s_barrier elision in single-wave workgroups).
__global__ __launch_bounds__(64) void w8a16_kernel(
    const int* __restrict__ W, const float* __restrict__ X,
    const float* __restrict__ scale, const float* __restrict__ bias,
    float* __restrict__ out)
{
    __shared__ __align__(16) int   Wl[2][BM][KC];  // raw int32, 8 KB
    __shared__ __align__(16) short Xl[2][16][KC];  // bf16, 4 KB

    const int lane = threadIdx.x;    // 0..63
    const int n    = lane & 15;      // MFMA: A row (out-ch) / B row (batch)
    const int kg   = lane >> 4;      // MFMA k-group; also staging row-quad
    const int o_base = blockIdx.x * BM;

    float4 xreg[4];
    f32x4  acc = {0.f, 0.f, 0.f, 0.f};

    // X: 4 instrs, 4 rows each (rows 4j+kg, 16 lanes x 16 B per row)
    #define LOADX(t)                                                              \
        _Pragma("unroll")                                                         \
        for (int j = 0; j < 4; ++j) {                                             \
            const int r = 4 * j + kg;                                             \
            xreg[j] = *reinterpret_cast<const float4*>(                           \
                X + (size_t)r * IN_F + (t) * KC + n * 4);                         \
        }

    // W: 4 x 1KB gloads; instr j stages rows 4j..4j+3 (lane L -> row 4j+(L>>4))
    #define GLOADW(buf, t)                                                        \
        _Pragma("unroll")                                                         \
        for (int j = 0; j < 4; ++j) {                                             \
            const int r = 4 * j + kg;                                             \
            const char* gp = (const char*)W                                       \
                + ((size_t)(o_base + r) * IN_F + (size_t)(t) * KC) * 4            \
                + ((n * 16) ^ swzW(r));                                           \
            gload16(gp, &Wl[buf][4 * j][0]);                                      \
        }

    #define XWRITE(buf)                                                           \
        _Pragma("unroll")                                                         \
        for (int j = 0; j < 4; ++j) {                                             \
            const int r = 4 * j + kg;                                             \
            short4 v;                                                             \
            v.x = bf(xreg[j].x); v.y = bf(xreg[j].y);                             \
            v.z = bf(xreg[j].z); v.w = bf(xreg[j].w);                             \
            char* p = (char*)&Xl[buf][r][0] + ((n * 8) ^ ((r & 7) << 4));         \
            *reinterpret_cast<short4*>(p) = v;                                    \
        }

    const int swzA  = swzW(n);
    const int swzAx = (n & 7) << 4;

    #define COMPUTE(buf)                                                          \
        _Pragma("unroll")                                                         \
        for (int s = 0; s < KC / 32; ++s) {                                       \
            const int o0 = (s * 128 + kg * 32) ^ swzA;                            \
            const int4 qa = *reinterpret_cast<const int4*>(                       \
                (const char*)&Wl[buf][n][0] + o0);                                \
            const int4 qb = *reinterpret_cast<const int4*>(                       \
                (const char*)&Wl[buf][n][0] + (o0 ^ 16));                         \
            bf16x8 a;                                                             \
            a[0]=bf((float)qa.x); a[1]=bf((float)qa.y);                           \
            a[2]=bf((float)qa.z); a[3]=bf((float)qa.w);                           \
            a[4]=bf((float)qb.x); a[5]=bf((float)qb.y);                           \
            a[6]=bf((float)qb.z); a[7]=bf((float)qb.w);                           \
            const int ox = (s * 64 + kg * 16) ^ swzAx;                            \
            bf16x8 b = *reinterpret_cast<const bf16x8*>(                          \
                (const char*)&Xl[buf][n][0] + ox);                                \
            acc = __builtin_amdgcn_mfma_f32_16x16x32_bf16(a, b, acc, 0, 0, 0);    \
        }

    // full drain + barrier (explicit waitcnt guards 1-wave barrier elision)
    #define TILE_SYNC()                                                           \
        asm volatile("s_waitcnt vmcnt(0) lgkmcnt(0)" ::: "memory");               \
        __syncthreads();

    // ---- prologue ----
    LOADX(0);
    GLOADW(0, 0);
    XWRITE(0);            // waits only on the 4 X loads (W gloads stay out)
    TILE_SYNC();

    // ---- main loop: one barrier per tile ----
    for (int t = 0; t < NT; ++t) {
        const int cur = t & 1;
        if (t + 1 < NT) {
            LOADX(t + 1);
            GLOADW(cur ^ 1, t + 1);   // in flight across COMPUTE(cur)
        }
        COMPUTE(cur);
        if (t + 1 < NT) { XWRITE(cur ^ 1); }
        TILE_SYNC();
    }

    // ---- epilogue: D col = lane&15 (batch n), row = kg*4 + reg (out-ch) ----
    const int o = o_base + kg * 4;
    const float4 sc = *reinterpret_cast<const float4*>(scale + o);
    const float4 bs = *reinterpret_cast<const float4*>(bias + o);
    float4 rr;
    rr.x = acc[0] * sc.x + bs.x;
    rr.y = acc[1] * sc.y + bs.y;
    rr.z = acc[2] * sc.z + bs.z;
    rr.w = acc[3] * sc.w + bs.w;
    *reinterpret_cast<float4*>(out + (size_t)n * OUT_F + o) = rr;

    #undef LOADX
    #undef GLOADW
    #undef XWRITE
    #undef COMPUTE
    #undef TILE_SYNC
}

extern "C" void kernel_launch(void* const* d_in, const int* in_sizes, int n_in,
                              void* d_out, int out_size, void* d_ws, size_t ws_size,
                              hipStream_t stream) {
    const float* x     = (const float*)d_in[0];
    const int*   w     = (const int*)  d_in[1];   // int8 values widened to int32 by harness
    const float* scale = (const float*)d_in[2];
    const float* bias  = (const float*)d_in[3];
    float* out = (float*)d_out;
    (void)in_sizes; (void)n_in; (void)d_ws; (void)ws_size; (void)out_size;

    w8a16_kernel<<<dim3(OUT_F / BM), dim3(64), 0, stream>>>(w, x, scale, bias, out);
}

// Round 13
// 106.651 us; speedup vs baseline: 1.0177x; 1.0177x over previous
//
#include <hip/hip_runtime.h>

#define IN_F  4096
#define OUT_F 32000
#define KC    128          // k per tile
#define NT    (IN_F / KC)  // 32 tiles
#define BM    16           // out-channels per block (one wave)

typedef __attribute__((ext_vector_type(8))) short bf16x8;
typedef __attribute__((ext_vector_type(4))) float f32x4;
typedef unsigned int u32;
typedef unsigned short u16;

__device__ __forceinline__ short bf(float f) {
    __bf16 h = (__bf16)f;
    short s;
    __builtin_memcpy(&s, &h, 2);
    return s;
}

// HBM -> LDS direct (16B/lane). LDS dest = wave-uniform base + lane*16;
// per-lane global source carries the swizzle. (Proven R7/R11.)
__device__ __forceinline__ void gload16(const void* g, void* l) {
    __builtin_amdgcn_global_load_lds(
        (const __attribute__((address_space(1))) u32*)g,
        (__attribute__((address_space(3))) u32*)l, 16, 0, 0);
}

// W-row swizzle (R7/R11-verified, 512-B rows): fragment ds_read_b128 pairs
// land 8 accesses on every one of the 32 banks (conflict-free minimum).
__device__ __forceinline__ int swzW(int r) {
    return ((r & 7) << 5) | (((r >> 3) & 1) << 4);
}

// ---------- pre-kernel: X (fp32 [16][4096]) -> fragment-ordered bf16 ----------
// Xt 16-B unit index g = c*64 + kg*16 + n  (c = k>>5, kg = (k>>3)&3), holding
// X[n][32c + 8kg .. +7] as 8 bf16. Main-kernel lane (n,kg) then loads its
// MFMA B-fragment for (tile t, slot s) at Xt + (4t+s)*1024 + lane*16 --
// one fully-coalesced 1-KB wave load per fragment. Total Xt = 128 KB in d_ws.
__global__ __launch_bounds__(256) void xprep_kernel(
    const float* __restrict__ X, u16* __restrict__ Xt)
{
    const int g = blockIdx.x * 256 + threadIdx.x;   // 0..8191
    const int c  = g >> 6;
    const int kg = (g >> 4) & 3;
    const int n  = g & 15;
    const int k0 = c * 32 + kg * 8;
    const float4 a = *reinterpret_cast<const float4*>(X + (size_t)n * IN_F + k0);
    const float4 b = *reinterpret_cast<const float4*>(X + (size_t)n * IN_F + k0 + 4);
    short4 lo, hi;
    lo.x = bf(a.x); lo.y = bf(a.y); lo.z = bf(a.z); lo.w = bf(a.w);
    hi.x = bf(b.x); hi.y = bf(b.y); hi.z = bf(b.z); hi.w = bf(b.w);
    *reinterpret_cast<short4*>(Xt + (size_t)g * 8)     = lo;
    *reinterpret_cast<short4*>(Xt + (size_t)g * 8 + 4) = hi;
}

// ---------- main kernel: 1 wave, 16 out-ch x 16 batch ----------
// W via global_load_lds (raw int32, double-buffered 16 KB, source-swizzled,
// 8 x 1-KB per tile, identical geometry to R11). X via direct coalesced
// fragment loads from Xt (4 x 1-KB per tile, L2-resident) -- no X staging
// chain. LDS 16 KB -> up to 10 blocks/CU; grid 2000 -> ~7.8 resident
// (R11-confirmed axis: independent block pipelines 2->4 gave +5.4%).
__global__ __launch_bounds__(64) void w8a16_kernel(
    const int* __restrict__ W, const u16* __restrict__ Xt,
    const float* __restrict__ scale, const float* __restrict__ bias,
    float* __restrict__ out)
{
    __shared__ __align__(16) int Wl[2][BM][KC];   // raw int32, 16 KB

    const int lane = threadIdx.x;    // 0..63
    const int n    = lane & 15;      // MFMA: A row (out-ch) / B row (batch)
    const int kg   = lane >> 4;      // MFMA k-group
    const int lo   = lane & 31;      // staging: 16-B quad within 512-B chunk
    const int hi   = lane >> 5;      // staging: row parity within instr
    const int o_base = blockIdx.x * BM;

    bf16x8 xf[4];                    // B-fragments for current tile
    f32x4  acc = {0.f, 0.f, 0.f, 0.f};

    // W: 8 x 1KB gloads; instr j stages rows {2j, 2j+1} (lane L -> row 2j+(L>>5))
    #define GLOADW(buf, t)                                                        \
        _Pragma("unroll")                                                         \
        for (int j = 0; j < 8; ++j) {                                             \
            const int r = 2 * j + hi;                                             \
            const char* gp = (const char*)W                                       \
                + ((size_t)(o_base + r) * IN_F + (size_t)(t) * KC) * 4            \
                + ((lo * 16) ^ swzW(r));                                          \
            gload16(gp, &Wl[buf][2 * j][0]);                                      \
        }

    // X: 4 coalesced 1-KB fragment loads (compiler-tracked; waits auto)
    #define LOADXF(t)                                                             \
        _Pragma("unroll")                                                         \
        for (int s = 0; s < 4; ++s) {                                             \
            xf[s] = *reinterpret_cast<const bf16x8*>(                             \
                Xt + ((size_t)(4 * (t) + s) * 64 + lane) * 8);                    \
        }

    const int swzA = swzW(n);

    #define COMPUTE(buf)                                                          \
        _Pragma("unroll")                                                         \
        for (int s = 0; s < KC / 32; ++s) {                                       \
            const int o0 = (s * 128 + kg * 32) ^ swzA;                            \
            const int4 qa = *reinterpret_cast<const int4*>(                       \
                (const char*)&Wl[buf][n][0] + o0);                                \
            const int4 qb = *reinterpret_cast<const int4*>(                       \
                (const char*)&Wl[buf][n][0] + (o0 ^ 16));                         \
            bf16x8 a;                                                             \
            a[0]=bf((float)qa.x); a[1]=bf((float)qa.y);                           \
            a[2]=bf((float)qa.z); a[3]=bf((float)qa.w);                           \
            a[4]=bf((float)qb.x); a[5]=bf((float)qb.y);                           \
            a[6]=bf((float)qb.z); a[7]=bf((float)qb.w);                           \
            acc = __builtin_amdgcn_mfma_f32_16x16x32_bf16(a, xf[s], acc, 0, 0, 0);\
        }

    // ---- prologue: W(0) in flight; X(0) fragments loaded ----
    GLOADW(0, 0);
    LOADXF(0);
    __syncthreads();      // drains tile-0 W into LDS

    // ---- main loop: one barrier per tile ----
    for (int t = 0; t < NT; ++t) {
        const int cur = t & 1;
        if (t + 1 < NT) { GLOADW(cur ^ 1, t + 1); }   // in flight across COMPUTE
        COMPUTE(cur);
        if (t + 1 < NT) { LOADXF(t + 1); }            // L2-resident, auto-waited
        __syncthreads();
    }

    // ---- epilogue: D col = lane&15 (batch n), row = kg*4 + reg (out-ch) ----
    const int o = o_base + kg * 4;
    const float4 sc = *reinterpret_cast<const float4*>(scale + o);
    const float4 bs = *reinterpret_cast<const float4*>(bias + o);
    float4 rr;
    rr.x = acc[0] * sc.x + bs.x;
    rr.y = acc[1] * sc.y + bs.y;
    rr.z = acc[2] * sc.z + bs.z;
    rr.w = acc[3] * sc.w + bs.w;
    *reinterpret_cast<float4*>(out + (size_t)n * OUT_F + o) = rr;

    #undef GLOADW
    #undef LOADXF
    #undef COMPUTE
}

extern "C" void kernel_launch(void* const* d_in, const int* in_sizes, int n_in,
                              void* d_out, int out_size, void* d_ws, size_t ws_size,
                              hipStream_t stream) {
    const float* x     = (const float*)d_in[0];
    const int*   w     = (const int*)  d_in[1];   // int8 values widened to int32 by harness
    const float* scale = (const float*)d_in[2];
    const float* bias  = (const float*)d_in[3];
    float* out = (float*)d_out;
    u16*   xt  = (u16*)d_ws;                      // 128 KB fragment-ordered X
    (void)in_sizes; (void)n_in; (void)ws_size; (void)out_size;

    xprep_kernel<<<dim3(32), dim3(256), 0, stream>>>(x, xt);
    w8a16_kernel<<<dim3(OUT_F / BM), dim3(64), 0, stream>>>(w, xt, scale, bias, out);
}

// Round 14
// 100.728 us; speedup vs baseline: 1.0776x; 1.0588x over previous
//
#include <hip/hip_runtime.h>

#define IN_F  4096
#define OUT_F 32000
#define KC    128          // k per tile
#define NT    (IN_F / KC)  // 32 tiles

typedef __attribute__((ext_vector_type(8))) short bf16x8;
typedef __attribute__((ext_vector_type(4))) float f32x4;
typedef unsigned int u32;

__device__ __forceinline__ short bf(float f) {
    __bf16 h = (__bf16)f;
    short s;
    __builtin_memcpy(&s, &h, 2);
    return s;
}

// HBM -> LDS direct (16B/lane). LDS dest = wave-uniform base + lane*16;
// per-lane global source carries the swizzle. (Proven in R7.)
__device__ __forceinline__ void gload16(const void* g, void* l) {
    __builtin_amdgcn_global_load_lds(
        (const __attribute__((address_space(1))) u32*)g,
        (__attribute__((address_space(3))) u32*)l, 16, 0, 0);
}

// W-row swizzle (R7-verified): fragment ds_read_b128 pairs land 8 accesses
// on every one of the 32 banks (conflict-free minimum).
__device__ __forceinline__ int swzW(int r) {
    return ((r & 7) << 5) | (((r >> 3) & 1) << 4);
}

// BEST CONFIG (R11, 93.3 us = 5.65 TB/s): block = 2 waves (128 thr),
// 32 out-ch x 16 batch, 40 KB LDS -> 4 independent block pipelines/CU,
// grid 1000. W via global_load_lds (raw int32, double-buffered,
// source-pre-swizzled, 8 x 1-KB per wave per tile); X reg-staged -> bf16
// LDS; X loads issued BEFORE W gloads; one __syncthreads per tile;
// int->bf16 convert fused into COMPUTE read path.
// Falsified alternatives: deeper prefetch (R4), KC=256 (R5), k-rotation
// (R6), counted-vmcnt/no-drain (R10), BM=16 small blocks (R12/R13).
__global__ __launch_bounds__(128) void w8a16_kernel(
    const int* __restrict__ W, const float* __restrict__ X,
    const float* __restrict__ scale, const float* __restrict__ bias,
    float* __restrict__ out)
{
    __shared__ __align__(16) int   Wl[2][32][KC];  // raw int32, 32 KB
    __shared__ __align__(16) short Xl[2][16][KC];  // bf16, 8 KB

    const int tid  = threadIdx.x;
    const int lane = tid & 63;
    const int wave = tid >> 6;    // 0..1
    const int n    = lane & 15;   // MFMA: A row (out-ch) / B row (batch)
    const int kg   = lane >> 4;   // MFMA k-group
    const int lo   = lane & 31;   // staging: 16-B quad within 512-B chunk
    const int hi   = lane >> 5;   // staging: row parity within instr
    const int o_base = blockIdx.x * 32;

    float4 xreg[4];
    f32x4  acc = {0.f, 0.f, 0.f, 0.f};

    // X: 4 loads/wave; wave w stages rows 8w..8w+7 (block covers 0..15)
    #define LOADX(t)                                                              \
        _Pragma("unroll")                                                         \
        for (int j = 0; j < 4; ++j) {                                             \
            const int r = wave * 8 + 2 * j + hi;                                  \
            xreg[j] = *reinterpret_cast<const float4*>(                           \
                X + (size_t)r * IN_F + (t) * KC + lo * 4);                        \
        }

    // W: 8 x 1KB gloads/wave; wave w owns rows 16w..16w+15
    #define GLOADW(buf, t)                                                        \
        _Pragma("unroll")                                                         \
        for (int j = 0; j < 8; ++j) {                                             \
            const int r  = wave * 16 + 2 * j + hi;                                \
            const char* gp = (const char*)W                                       \
                + ((size_t)(o_base + r) * IN_F + (size_t)(t) * KC) * 4            \
                + ((lo * 16) ^ swzW(r));                                          \
            gload16(gp, &Wl[buf][wave * 16 + 2 * j][0]);                          \
        }

    #define XWRITE(buf)                                                           \
        _Pragma("unroll")                                                         \
        for (int j = 0; j < 4; ++j) {                                             \
            const int r = wave * 8 + 2 * j + hi;                                  \
            short4 v;                                                             \
            v.x = bf(xreg[j].x); v.y = bf(xreg[j].y);                             \
            v.z = bf(xreg[j].z); v.w = bf(xreg[j].w);                             \
            char* p = (char*)&Xl[buf][r][0] + ((lo * 8) ^ ((r & 7) << 4));        \
            *reinterpret_cast<short4*>(p) = v;                                    \
        }

    const int rA    = wave * 16 + n;
    const int swzA  = swzW(rA);
    const int swzAx = (n & 7) << 4;

    #define COMPUTE(buf)                                                          \
        _Pragma("unroll")                                                         \
        for (int s = 0; s < KC / 32; ++s) {                                       \
            const int o0 = (s * 128 + kg * 32) ^ swzA;                            \
            const int4 qa = *reinterpret_cast<const int4*>(                       \
                (const char*)&Wl[buf][rA][0] + o0);                               \
            const int4 qb = *reinterpret_cast<const int4*>(                       \
                (const char*)&Wl[buf][rA][0] + (o0 ^ 16));                        \
            bf16x8 a;                                                             \
            a[0]=bf((float)qa.x); a[1]=bf((float)qa.y);                           \
            a[2]=bf((float)qa.z); a[3]=bf((float)qa.w);                           \
            a[4]=bf((float)qb.x); a[5]=bf((float)qb.y);                           \
            a[6]=bf((float)qb.z); a[7]=bf((float)qb.w);                           \
            const int ox = (s * 64 + kg * 16) ^ swzAx;                            \
            bf16x8 b = *reinterpret_cast<const bf16x8*>(                          \
                (const char*)&Xl[buf][n][0] + ox);                                \
            acc = __builtin_amdgcn_mfma_f32_16x16x32_bf16(a, b, acc, 0, 0, 0);    \
        }

    // ---- prologue ----
    LOADX(0);
    GLOADW(0, 0);
    XWRITE(0);            // waits only on the 4 X loads (8 W gloads stay out)
    __syncthreads();      // drains tile-0 W into LDS

    // ---- main loop: one barrier per tile ----
    for (int t = 0; t < NT; ++t) {
        const int cur = t & 1;
        if (t + 1 < NT) {
            LOADX(t + 1);
            GLOADW(cur ^ 1, t + 1);   // in flight across COMPUTE(cur)
        }
        COMPUTE(cur);
        if (t + 1 < NT) { XWRITE(cur ^ 1); }
        __syncthreads();
    }

    // ---- epilogue: D col = lane&15 (batch n), row = kg*4 + reg (out-ch) ----
    const int o = o_base + wave * 16 + kg * 4;
    const float4 sc = *reinterpret_cast<const float4*>(scale + o);
    const float4 bs = *reinterpret_cast<const float4*>(bias + o);
    float4 rr;
    rr.x = acc[0] * sc.x + bs.x;
    rr.y = acc[1] * sc.y + bs.y;
    rr.z = acc[2] * sc.z + bs.z;
    rr.w = acc[3] * sc.w + bs.w;
    *reinterpret_cast<float4*>(out + (size_t)n * OUT_F + o) = rr;

    #undef LOADX
    #undef GLOADW
    #undef XWRITE
    #undef COMPUTE
}

extern "C" void kernel_launch(void* const* d_in, const int* in_sizes, int n_in,
                              void* d_out, int out_size, void* d_ws, size_t ws_size,
                              hipStream_t stream) {
    const float* x     = (const float*)d_in[0];
    const int*   w     = (const int*)  d_in[1];   // int8 values widened to int32 by harness
    const float* scale = (const float*)d_in[2];
    const float* bias  = (const float*)d_in[3];
    float* out = (float*)d_out;
    (void)in_sizes; (void)n_in; (void)d_ws; (void)ws_size; (void)out_size;

    w8a16_kernel<<<dim3(OUT_F / 32), dim3(128), 0, stream>>>(w, x, scale, bias, out);
}